// Round 15
// baseline (160.093 us; speedup 1.0000x reference)
//
#include <hip/hip_runtime.h>

#define B_ 8
#define T_ 1024
#define CG_ 256
#define CAP2 24
#define SENT_J 1025u

// ---------------- pack: x (8,1024,1024) f32 -> tok rows (B*Cg, T) u8 ----------------
__global__ __launch_bounds__(256) void pack_kernel(const float* __restrict__ x,
                                                   unsigned char* __restrict__ tok){
  __shared__ unsigned char tl[256][80];
  const int b  = blockIdx.x >> 4;
  const int t0 = (blockIdx.x & 15) << 6;
  const int g  = threadIdx.x;
  const float* xb = x + ((size_t)(b*T_ + t0) * 1024) + g*4;
  for (int tt = 0; tt < 64; tt++){
    const float4 v = *reinterpret_cast<const float4*>(xb + (size_t)tt*1024);
    unsigned int t = (v.x>0.f?1u:0u) | (v.y>0.f?2u:0u) | (v.z>0.f?4u:0u) | (v.w>0.f?8u:0u);
    tl[g][tt] = (unsigned char)t;
  }
  __syncthreads();
  const int gg  = threadIdx.x >> 2;
  const int off = (threadIdx.x & 3) * 16;
  for (int it = 0; it < 4; it++){
    const int g2 = gg + it*64;
    const uint4 w = *reinterpret_cast<const uint4*>(&tl[g2][off]);
    *reinterpret_cast<uint4*>(tok + (size_t)(b*CG_ + g2)*T_ + t0 + off) = w;
  }
}

// Bigram-sparse ROSA DP: TWO rows per wave (row A lanes 0-31, row B lanes 32-63).
// Each per-lane instruction advances both rows; one ds_read gathers both rows.
// Per row the semantics are identical to the R14-passed kernel: pipelined gather
// (1 step ahead), stamp DP (fresh stamp i-1 -> run+1, stale -> 2), precomputed
// run-1 keys (prevocc), deferred argmax via 3-DPP 8-group maxes + M8.
struct alignas(16) RowLds {
  unsigned int   val[1028];     // cells 0..1023; [1024] dummy-read; [1025] trash-write
                                // build alias: val[0..255] = bucket counters
  unsigned char  t[1040];       // tokens + pad
  unsigned short bg[256*CAP2];  // buckets: plain j, sentinel 1025       (12288 B)
  unsigned int   M8[320];       // [64][5]: cols 0..2 = 8-lane-group maxes
  unsigned int   trash[64];
};                              // 18976 B; 4 rows/block = 75904 B -> 2 blocks/CU

__global__ __launch_bounds__(128, 1) void rosa_bg5_kernel(const unsigned char* __restrict__ tok,
                                                          unsigned char* __restrict__ pred){
  __shared__ RowLds S[4];
  const int wave = threadIdx.x >> 6;
  const unsigned int lane = threadIdx.x & 63u;
  const unsigned int half = lane >> 5;          // 0 = row A, 1 = row B
  const unsigned int ll   = lane & 31u;         // row-local lane
  const int rowA = blockIdx.x * 4 + wave * 2;
  const int rowB = rowA + 1;
  RowLds& RA = S[wave*2 + 0];
  RowLds& RB = S[wave*2 + 1];
  RowLds* const myR = half ? &RB : &RA;

  // ---- stage tokens for both rows + pad ----
  { const uint4 vA = *reinterpret_cast<const uint4*>(tok + (size_t)rowA*T_ + lane*16);
    *reinterpret_cast<uint4*>(&RA.t[lane*16]) = vA;
    const uint4 vB = *reinterpret_cast<const uint4*>(tok + (size_t)rowB*T_ + lane*16);
    *reinterpret_cast<uint4*>(&RB.t[lane*16]) = vB;
    if (lane == 0u){
      *reinterpret_cast<uint4*>(&RA.t[1024]) = make_uint4(0,0,0,0);
      *reinterpret_cast<uint4*>(&RB.t[1024]) = make_uint4(0,0,0,0);
    } }
  // zero bucket counters (val[0..255] alias), fill bg sentinels -- both rows
  { uint4* pA = reinterpret_cast<uint4*>(RA.val);
    uint4* pB = reinterpret_cast<uint4*>(RB.val);
    pA[lane] = make_uint4(0,0,0,0);
    pB[lane] = make_uint4(0,0,0,0);
    const unsigned int s2 = SENT_J | (SENT_J << 16);
    const uint4 s4 = make_uint4(s2,s2,s2,s2);
    uint4* bA = reinterpret_cast<uint4*>(RA.bg);
    uint4* bB = reinterpret_cast<uint4*>(RB.bg);
    #pragma unroll
    for (int m = 0; m < 12; m++){ bA[m*64 + lane] = s4; bB[m*64 + lane] = s4; } }

  // tokens -> registers (both rows)
  unsigned int vtokkA[16], vtokkB[16];
  #pragma unroll
  for (int k = 0; k < 16; k++){ vtokkA[k] = RA.t[k*64 + lane]; vtokkB[k] = RB.t[k*64 + lane]; }

  // build buckets (full wave per row, sequential)
  #pragma unroll
  for (int k = 0; k < 16; k++){
    const unsigned int j = (unsigned)k*64u + lane;
    if (j >= 1u){
      { const unsigned int v2 = ((unsigned)RA.t[j-1] << 4) | (unsigned)RA.t[j];
        const unsigned int r = atomicAdd(&RA.val[v2], 1u);
        if (r < (unsigned)CAP2) RA.bg[v2*CAP2 + r] = (unsigned short)j; }
      { const unsigned int v2 = ((unsigned)RB.t[j-1] << 4) | (unsigned)RB.t[j];
        const unsigned int r = atomicAdd(&RB.val[v2], 1u);
        if (r < (unsigned)CAP2) RB.bg[v2*CAP2 + r] = (unsigned short)j; }
    }
  }

  // ---- build prevocc run-1 keys for both rows ----
  const unsigned long long below = (1ull << lane) - 1ull;
  unsigned int pvkA[16], pvkB[16];
  {
    int lp1c = -1;
    #pragma unroll 1
    for (int c = 0; c < 16; c++){
      const unsigned int tj = vtokkA[c];
      const unsigned long long b0 = __ballot((tj & 1u) != 0u);
      const unsigned long long b1 = __ballot((tj & 2u) != 0u);
      const unsigned long long b2 = __ballot((tj & 4u) != 0u);
      const unsigned long long b3 = __ballot((tj & 8u) != 0u);
      unsigned long long mm = ((tj & 1u) ? b0 : ~b0) & ((tj & 2u) ? b1 : ~b1)
                            & ((tj & 4u) ? b2 : ~b2) & ((tj & 8u) ? b3 : ~b3);
      const unsigned long long mlo = mm & below;
      const int pin = 63 - __builtin_clzll(mlo | 1ull);
      const int pg  = __builtin_amdgcn_ds_bpermute((int)(tj << 2), lp1c);
      const int pv  = mlo ? (c*64 + pin) : pg;
      pvkA[c] = (pv < 0) ? 0u : (1024u + (unsigned)pv);
      unsigned long long mv = ((lane & 1u) ? b0 : ~b0) & ((lane & 2u) ? b1 : ~b1)
                            & ((lane & 4u) ? b2 : ~b2) & ((lane & 8u) ? b3 : ~b3);
      if (mv) lp1c = c*64 + 63 - __builtin_clzll(mv);
    }
  }
  {
    int lp1c = -1;
    #pragma unroll 1
    for (int c = 0; c < 16; c++){
      const unsigned int tj = vtokkB[c];
      const unsigned long long b0 = __ballot((tj & 1u) != 0u);
      const unsigned long long b1 = __ballot((tj & 2u) != 0u);
      const unsigned long long b2 = __ballot((tj & 4u) != 0u);
      const unsigned long long b3 = __ballot((tj & 8u) != 0u);
      unsigned long long mm = ((tj & 1u) ? b0 : ~b0) & ((tj & 2u) ? b1 : ~b1)
                            & ((tj & 4u) ? b2 : ~b2) & ((tj & 8u) ? b3 : ~b3);
      const unsigned long long mlo = mm & below;
      const int pin = 63 - __builtin_clzll(mlo | 1ull);
      const int pg  = __builtin_amdgcn_ds_bpermute((int)(tj << 2), lp1c);
      const int pv  = mlo ? (c*64 + pin) : pg;
      pvkB[c] = (pv < 0) ? 0u : (1024u + (unsigned)pv);
      unsigned long long mv = ((lane & 1u) ? b0 : ~b0) & ((lane & 2u) ? b1 : ~b1)
                            & ((lane & 4u) ? b2 : ~b2) & ((lane & 8u) ? b3 : ~b3);
      if (mv) lp1c = c*64 + 63 - __builtin_clzll(mv);
    }
  }

  // init val stamps to 0xFFFF (overwrites counter alias; incl slots 1024..1027)
  { const uint4 z = make_uint4(0xFFFF0000u,0xFFFF0000u,0xFFFF0000u,0xFFFF0000u);
    uint4* pA = reinterpret_cast<uint4*>(RA.val);
    uint4* pB = reinterpret_cast<uint4*>(RB.val);
    #pragma unroll
    for (int m = 0; m < 4; m++){ pA[m*64 + lane] = z; pB[m*64 + lane] = z; }
    if (lane == 0u){ pA[256] = z; pB[256] = z; } }

  // ---- per-lane bases ----
  const bool lane24 = (ll < (unsigned)CAP2);
  const bool realw  = ((ll & 7u) == 7u) && (ll < 24u);   // ll 7/15/23 -> cols 0..2
  unsigned int* const wbase0 = realw ? &myR->M8[ll >> 3] : &myR->trash[ll];
  const unsigned int wstep = realw ? 5u : 0u;
  unsigned int* const valp = myR->val;
  unsigned short* const bgl = myR->bg + ll;              // + v2*CAP2 per step

  // ---- prologue: buckets for steps 0,1; primed gather for step 0 ----
  const int x0A = __builtin_amdgcn_readlane((int)vtokkA[0], 0);
  const int x1A = __builtin_amdgcn_readlane((int)vtokkA[0], 1);
  const int x0B = __builtin_amdgcn_readlane((int)vtokkB[0], 0);
  const int x1B = __builtin_amdgcn_readlane((int)vtokkB[0], 1);
  unsigned int enA, enB, gA;
  { const unsigned int bn0 = half ? (unsigned)x0B : (unsigned)x0A;          // (0<<4)|x0
    enA = (unsigned int)*(bgl + bn0 * CAP2);
    const unsigned int bn1A = (((unsigned)x0A << 4) | (unsigned)x1A);
    const unsigned int bn1B = (((unsigned)x0B << 4) | (unsigned)x1B);
    const unsigned int bn1 = half ? bn1B : bn1A;
    enB = (unsigned int)*(bgl + bn1 * CAP2);
    const unsigned int jl0 = lane24 ? enA : SENT_J;
    gA = valp[jl0 - 1u]; }
  int s_xA1 = x1A, s_xB1 = x1B;                 // x[i+1] per row

#define RSTEP(I_, NTA_, NTB_) do {                                                \
    const int i_ = (I_);                                                          \
    const unsigned int jlA = lane24 ? enA : SENT_J;                               \
    const int s_xA2 = (NTA_);                                                     \
    const int s_xB2 = (NTB_);                                                     \
    const unsigned int bnA = (((unsigned)s_xA1 << 4) | (unsigned)s_xA2);          \
    const unsigned int bnB = (((unsigned)s_xB1 << 4) | (unsigned)s_xB2);          \
    const unsigned int v_bn = half ? bnB : bnA;                                   \
    const unsigned int enN = (unsigned int)*(bgl + v_bn * CAP2);                  \
    const unsigned int d = gA - (((unsigned)(i_ - 1)) << 16);                     \
    const unsigned int rn = (d <= 1024u) ? (d + 1u) : 2u;                         \
    valp[jlA] = (((unsigned)i_) << 16) | rn;                                      \
    const unsigned int jlB = lane24 ? enB : SENT_J;                               \
    const unsigned int gB = valp[jlB - 1u];                                       \
    unsigned int key = (rn << 10) | jlA;                                          \
    key = (jlA < (unsigned)i_) ? key : 0u;                                        \
    int bb = (int)key, tt;                                                        \
    tt = __builtin_amdgcn_mov_dpp(bb, 0x111, 0xf, 0xf, true); bb = ((unsigned)tt > (unsigned)bb) ? tt : bb; \
    tt = __builtin_amdgcn_mov_dpp(bb, 0x112, 0xf, 0xf, true); bb = ((unsigned)tt > (unsigned)bb) ? tt : bb; \
    tt = __builtin_amdgcn_mov_dpp(bb, 0x114, 0xf, 0xf, true); bb = ((unsigned)tt > (unsigned)bb) ? tt : bb; \
    *wptr = (unsigned)bb;                                                         \
    wptr += wstep;                                                                \
    enA = enB; enB = enN; gA = gB;                                                \
    s_xA1 = s_xA2; s_xB1 = s_xB2;                                                 \
  } while(0)

  #pragma unroll
  for (int i0 = 0; i0 < 16; i0++){
    unsigned int* wptr = wbase0;
    #pragma unroll 2
    for (int di = 0; di < 62; di++){
      RSTEP(i0*64 + di, __builtin_amdgcn_readlane((int)vtokkA[i0], di + 2),
                        __builtin_amdgcn_readlane((int)vtokkB[i0], di + 2));
    }
    RSTEP(i0*64 + 62, __builtin_amdgcn_readlane((int)vtokkA[(i0+1) & 15], (i0 < 15) ? 0 : 62),
                      __builtin_amdgcn_readlane((int)vtokkB[(i0+1) & 15], (i0 < 15) ? 0 : 62));
    RSTEP(i0*64 + 63, __builtin_amdgcn_readlane((int)vtokkA[(i0+1) & 15], (i0 < 15) ? 1 : 63),
                      __builtin_amdgcn_readlane((int)vtokkB[(i0+1) & 15], (i0 < 15) ? 1 : 63));
    // block epilogue: lane s finalizes step i0*64+s for row A, then row B
    const unsigned int b5 = lane * 5u;
    { unsigned int ab = RA.M8[b5];
      { const unsigned int v1 = RA.M8[b5 + 1u]; ab = v1 > ab ? v1 : ab; }
      { const unsigned int v2 = RA.M8[b5 + 2u]; ab = v2 > ab ? v2 : ab; }
      { const unsigned int v3 = pvkA[i0];       ab = v3 > ab ? v3 : ab; }
      unsigned int pidx = (ab & 1023u) + 1u;
      pidx = pidx > 1023u ? 1023u : pidx;
      const unsigned int pt = RA.t[pidx];
      pred[(size_t)rowA*T_ + i0*64 + lane] = (unsigned char)((ab >= 1024u) ? pt : 0u); }
    { unsigned int ab = RB.M8[b5];
      { const unsigned int v1 = RB.M8[b5 + 1u]; ab = v1 > ab ? v1 : ab; }
      { const unsigned int v2 = RB.M8[b5 + 2u]; ab = v2 > ab ? v2 : ab; }
      { const unsigned int v3 = pvkB[i0];       ab = v3 > ab ? v3 : ab; }
      unsigned int pidx = (ab & 1023u) + 1u;
      pidx = pidx > 1023u ? 1023u : pidx;
      const unsigned int pt = RB.t[pidx];
      pred[(size_t)rowB*T_ + i0*64 + lane] = (unsigned char)((ab >= 1024u) ? pt : 0u); }
  }
#undef RSTEP
}

// ---------------- expand: pred (B*Cg, T) u8 -> out (B,T,C) f32 ----------------
__global__ __launch_bounds__(256) void expand_kernel(const unsigned char* __restrict__ pred,
                                                     const float* __restrict__ emb0,
                                                     const float* __restrict__ emb1,
                                                     float* __restrict__ out){
  __shared__ unsigned char pl[64][80];
  const int bid = blockIdx.x;
  const int g0 = (bid & 3) << 6;
  const int t0 = ((bid >> 2) & 15) << 6;
  const int b  = bid >> 6;
  const int k  = threadIdx.x;
  {
    const int gg = k >> 2, off = (k & 3) * 16;
    const uint4 v = *reinterpret_cast<const uint4*>(pred + (size_t)(b*CG_ + g0 + gg)*T_ + t0 + off);
    *reinterpret_cast<uint4*>(&pl[gg][off]) = v;
  }
  __syncthreads();
  const int gg = k & 63;
  const int w  = k >> 6;
  const float4 e0 = *reinterpret_cast<const float4*>(emb0 + (g0+gg)*4);
  const float4 e1 = *reinterpret_cast<const float4*>(emb1 + (g0+gg)*4);
  for (int it = 0; it < 16; it++){
    const int tt = it*4 + w;
    const unsigned int pb = pl[gg][tt];
    float4 o;
    o.x = (pb & 1u) ? e1.x : e0.x;
    o.y = (pb & 2u) ? e1.y : e0.y;
    o.z = (pb & 4u) ? e1.z : e0.z;
    o.w = (pb & 8u) ? e1.w : e0.w;
    *reinterpret_cast<float4*>(out + (size_t)(b*T_ + t0 + tt)*1024 + (g0+gg)*4) = o;
  }
}

extern "C" void kernel_launch(void* const* d_in, const int* in_sizes, int n_in,
                              void* d_out, int out_size, void* d_ws, size_t ws_size,
                              hipStream_t stream){
  const float* x    = (const float*)d_in[0];
  const float* emb0 = (const float*)d_in[1];
  const float* emb1 = (const float*)d_in[2];
  float* out = (float*)d_out;
  unsigned char* tok  = (unsigned char*)d_ws;
  unsigned char* pred = tok + (size_t)B_*CG_*T_;
  pack_kernel<<<128, 256, 0, stream>>>(x, tok);
  rosa_bg5_kernel<<<(B_*CG_)/4, 128, 0, stream>>>(tok, pred);
  expand_kernel<<<512, 256, 0, stream>>>(pred, emb0, emb1, out);
}